// Round 4
// baseline (512.291 us; speedup 1.0000x reference)
//
#include <hip/hip_runtime.h>
#include <math.h>

// ---- float <-> order-preserving uint key (for global min/max via atomics) ----
static __device__ __forceinline__ unsigned fkey(float f) {
  unsigned u = __float_as_uint(f);
  return (u & 0x80000000u) ? ~u : (u | 0x80000000u);
}
static __device__ __forceinline__ float funkey(unsigned u) {
  unsigned b = (u & 0x80000000u) ? (u & 0x7FFFFFFFu) : ~u;
  return __uint_as_float(b);
}

__global__ __launch_bounds__(64) void init_minmax(unsigned* ws) {
  if (threadIdx.x == 0) { ws[0] = 0xFFFFFFFFu; ws[1] = 0u; }
}

// one float4 per thread, exactly covers ndep/4
__global__ __launch_bounds__(256) void minmax_kernel(const float4* __restrict__ d,
                                                     unsigned* __restrict__ ws, int n4) {
  int i = blockIdx.x * 256 + threadIdx.x;
  float lmin = INFINITY, lmax = -INFINITY;
  if (i < n4) {
    float4 v = d[i];
    lmin = fminf(fminf(v.x, v.y), fminf(v.z, v.w));
    lmax = fmaxf(fmaxf(v.x, v.y), fmaxf(v.z, v.w));
  }
#pragma unroll
  for (int off = 32; off; off >>= 1) {
    lmin = fminf(lmin, __shfl_xor(lmin, off));
    lmax = fmaxf(lmax, __shfl_xor(lmax, off));
  }
  if ((threadIdx.x & 63) == 0) {
    atomicMin(&ws[0], fkey(lmin));
    atomicMax(&ws[1], fkey(lmax));
  }
}

// ---- DPP cross-lane helpers (VALU, no DS-unit traffic) ----
template <int CTRL, int RM, int BM>
static __device__ __forceinline__ float updf(float oldv, float src) {
  return __int_as_float(__builtin_amdgcn_update_dpp(
      __float_as_int(oldv), __float_as_int(src), CTRL, RM, BM, false));
}

static __device__ __forceinline__ float mul_scan64(float x) {
  x *= updf<0x111, 0xf, 0xf>(1.0f, x);  // row_shr:1
  x *= updf<0x112, 0xf, 0xf>(1.0f, x);  // row_shr:2
  x *= updf<0x114, 0xf, 0xe>(1.0f, x);  // row_shr:4
  x *= updf<0x118, 0xf, 0xc>(1.0f, x);  // row_shr:8
  x *= updf<0x142, 0xa, 0xf>(1.0f, x);  // row_bcast:15 -> rows 1,3
  x *= updf<0x143, 0xc, 0xf>(1.0f, x);  // row_bcast:31 -> rows 2,3
  return x;
}
static __device__ __forceinline__ float sum64_lane63(float x) {
  x += updf<0x111, 0xf, 0xf>(0.0f, x);
  x += updf<0x112, 0xf, 0xf>(0.0f, x);
  x += updf<0x114, 0xf, 0xe>(0.0f, x);
  x += updf<0x118, 0xf, 0xc>(0.0f, x);
  x += updf<0x142, 0xa, 0xf>(0.0f, x);
  x += updf<0x143, 0xc, 0xf>(0.0f, x);
  return x;
}
static __device__ __forceinline__ float readlane63(float x) {
  return __int_as_float(__builtin_amdgcn_readlane(__float_as_int(x), 63));
}

// Kernel A: per-ray scan + scalar outputs + coef handoff. No colors.
__global__ __launch_bounds__(256) void march_lite(
    const float* __restrict__ dens, const float* __restrict__ depths,
    const float* __restrict__ grads, float* __restrict__ out,
    float* __restrict__ coef_ws, const unsigned* __restrict__ mm,
    size_t o_depth, size_t o_w, size_t o_grad)
{
  const int lane = threadIdx.x & 63;
  const size_t ray = (size_t)blockIdx.x * 4 + (threadIdx.x >> 6);

  const float d   = depths[ray * 64 + lane];
  const float den = dens  [ray * 64 + lane];
  const float* gp = grads + ray * 192 + (size_t)lane * 3;
  const float g0 = gp[0], g1 = gp[1], g2 = gp[2];

  const float dn    = __shfl_down(d, 1);
  const float denn  = __shfl_down(den, 1);
  const float delta = dn - d;
  const float dm    = 0.5f * (den + denn) - 1.0f;
  const float sp    = fmaxf(dm, 0.0f) + log1pf(expf(-fabsf(dm)));  // softplus
  const float dd    = sp * delta;
  const float alpha = 1.0f - expf(-dd);
  const float t     = (1.0f - alpha) + 1e-10f;

  const float p = mul_scan64(t);
  float excl = __shfl_up(p, 1);
  if (lane == 0) excl = 1.0f;
  const float w = (lane < 63) ? alpha * excl : 0.0f;

  if (lane < 63) out[o_w + ray * 63 + lane] = w;

  float wprev = __shfl_up(w, 1);
  if (lane == 0) wprev = 0.0f;
  const float coef = 0.5f * (w + wprev);
  coef_ws[ray * 64 + lane] = coef;

  const float wt = readlane63(sum64_lane63(w));
  const float s1 = readlane63(sum64_lane63(coef * d));
  const float s2 = readlane63(sum64_lane63(coef * g0));
  const float s3 = readlane63(sum64_lane63(coef * g1));
  const float s4 = readlane63(sum64_lane63(coef * g2));

  if (lane == 0) {
    float cd = s1 / wt;
    if (cd != cd) cd = INFINITY;
    cd = fminf(fmaxf(cd, funkey(mm[0])), funkey(mm[1]));
    out[o_depth + ray] = cd;
    const float add = 1.0f - wt;
    float* og = out + o_grad + ray * 3;
    og[0] = s2 + add;
    og[1] = s3 + add;
    og[2] = s4 + add;
  }
}

// Kernel B: pure color stream + weighted reduce. One wave per ray.
__global__ __launch_bounds__(256) void rgb_kernel(
    const float* __restrict__ colors, const float* __restrict__ coef_ws,
    float* __restrict__ out)
{
  const int lane = threadIdx.x & 63;
  const size_t ray = (size_t)blockIdx.x * 4 + (threadIdx.x >> 6);

  const float coef = coef_ws[ray * 64 + lane];

  // transposed loads: instr k reads contiguous 1 KB; lane holds
  // sample s = k*8 + (lane>>3), channels (lane&7)*4 .. +3
  const float4* cp = (const float4*)(colors + ray * 2048);
  float4 col[8];
#pragma unroll
  for (int k = 0; k < 8; ++k) col[k] = cp[(size_t)k * 64 + lane];

  float a0 = 0.f, a1 = 0.f, a2 = 0.f, a3 = 0.f;
  const int sbase = lane >> 3;
#pragma unroll
  for (int k = 0; k < 8; ++k) {
    const float cf = __shfl(coef, k * 8 + sbase);
    a0 = fmaf(cf, col[k].x, a0);
    a1 = fmaf(cf, col[k].y, a1);
    a2 = fmaf(cf, col[k].z, a2);
    a3 = fmaf(cf, col[k].w, a3);
  }
  a0 += updf<0x128, 0xf, 0xf>(0.0f, a0);   // + lane^8 (row_ror:8)
  a1 += updf<0x128, 0xf, 0xf>(0.0f, a1);
  a2 += updf<0x128, 0xf, 0xf>(0.0f, a2);
  a3 += updf<0x128, 0xf, 0xf>(0.0f, a3);
#pragma unroll
  for (int off = 16; off <= 32; off <<= 1) {
    a0 += __shfl_xor(a0, off);
    a1 += __shfl_xor(a1, off);
    a2 += __shfl_xor(a2, off);
    a3 += __shfl_xor(a3, off);
  }
  if (lane < 8) {
    float4 o;
    o.x = fmaf(a0, 2.0f, -1.0f);
    o.y = fmaf(a1, 2.0f, -1.0f);
    o.z = fmaf(a2, 2.0f, -1.0f);
    o.w = fmaf(a3, 2.0f, -1.0f);
    ((float4*)(out + ray * 32))[lane] = o;
  }
}

extern "C" void kernel_launch(void* const* d_in, const int* in_sizes, int n_in,
                              void* d_out, int out_size, void* d_ws, size_t ws_size,
                              hipStream_t stream) {
  const float* colors = (const float*)d_in[0];
  const float* dens   = (const float*)d_in[1];
  const float* depths = (const float*)d_in[2];
  const float* grads  = (const float*)d_in[3];
  float* out = (float*)d_out;
  unsigned* ws = (unsigned*)d_ws;
  float* coef_ws = (float*)d_ws + 16;   // 64B offset keeps alignment

  const int ndep  = in_sizes[2];        // B*R*S = nrays*64
  const int nrays = ndep / 64;          // 65536
  const int C     = in_sizes[0] / ndep; // 32

  const size_t o_depth = (size_t)nrays * C;
  const size_t o_w     = o_depth + (size_t)nrays;
  const size_t o_grad  = o_w + (size_t)nrays * 63;

  const int n4 = ndep / 4;
  hipLaunchKernelGGL(init_minmax, dim3(1), dim3(64), 0, stream, ws);
  hipLaunchKernelGGL(minmax_kernel, dim3((n4 + 255) / 256), dim3(256), 0, stream,
                     (const float4*)depths, ws, n4);
  hipLaunchKernelGGL(march_lite, dim3(nrays / 4), dim3(256), 0, stream,
                     dens, depths, grads, out, coef_ws, ws, o_depth, o_w, o_grad);
  hipLaunchKernelGGL(rgb_kernel, dim3(nrays / 4), dim3(256), 0, stream,
                     colors, coef_ws, out);
}

// Round 5
// 154.405 us; speedup vs baseline: 3.3179x; 3.3179x over previous
//
#include <hip/hip_runtime.h>
#include <math.h>

// ---- float <-> order-preserving uint key (for global min/max via atomics) ----
static __device__ __forceinline__ unsigned fkey(float f) {
  unsigned u = __float_as_uint(f);
  return (u & 0x80000000u) ? ~u : (u | 0x80000000u);
}
static __device__ __forceinline__ float funkey(unsigned u) {
  unsigned b = (u & 0x80000000u) ? (u & 0x7FFFFFFFu) : ~u;
  return __uint_as_float(b);
}

__global__ __launch_bounds__(64) void init_minmax(unsigned* ws) {
  if (threadIdx.x == 0) { ws[0] = 0xFFFFFFFFu; ws[1] = 0u; }
}

// grid-stride, wave reduce -> block reduce in LDS -> ONE atomic pair per block
__global__ __launch_bounds__(256) void minmax_kernel(const float4* __restrict__ d,
                                                     unsigned* __restrict__ ws, int n4) {
  __shared__ float smin[4], smax[4];
  int idx = blockIdx.x * 256 + threadIdx.x;
  int stride = gridDim.x * 256;
  float lmin = INFINITY, lmax = -INFINITY;
  for (int i = idx; i < n4; i += stride) {
    float4 v = d[i];
    lmin = fminf(lmin, fminf(fminf(v.x, v.y), fminf(v.z, v.w)));
    lmax = fmaxf(lmax, fmaxf(fmaxf(v.x, v.y), fmaxf(v.z, v.w)));
  }
#pragma unroll
  for (int off = 32; off; off >>= 1) {
    lmin = fminf(lmin, __shfl_xor(lmin, off));
    lmax = fmaxf(lmax, __shfl_xor(lmax, off));
  }
  const int wid = threadIdx.x >> 6;
  if ((threadIdx.x & 63) == 0) { smin[wid] = lmin; smax[wid] = lmax; }
  __syncthreads();
  if (threadIdx.x == 0) {
    float bmin = fminf(fminf(smin[0], smin[1]), fminf(smin[2], smin[3]));
    float bmax = fmaxf(fmaxf(smax[0], smax[1]), fmaxf(smax[2], smax[3]));
    atomicMin(&ws[0], fkey(bmin));
    atomicMax(&ws[1], fkey(bmax));
  }
}

// ---- DPP cross-lane helpers (VALU, no DS-unit traffic) ----
template <int CTRL, int RM, int BM>
static __device__ __forceinline__ float updf(float oldv, float src) {
  return __int_as_float(__builtin_amdgcn_update_dpp(
      __float_as_int(oldv), __float_as_int(src), CTRL, RM, BM, false));
}

static __device__ __forceinline__ float mul_scan64(float x) {
  x *= updf<0x111, 0xf, 0xf>(1.0f, x);  // row_shr:1
  x *= updf<0x112, 0xf, 0xf>(1.0f, x);  // row_shr:2
  x *= updf<0x114, 0xf, 0xe>(1.0f, x);  // row_shr:4
  x *= updf<0x118, 0xf, 0xc>(1.0f, x);  // row_shr:8
  x *= updf<0x142, 0xa, 0xf>(1.0f, x);  // row_bcast:15 -> rows 1,3
  x *= updf<0x143, 0xc, 0xf>(1.0f, x);  // row_bcast:31 -> rows 2,3
  return x;
}
static __device__ __forceinline__ float sum64_lane63(float x) {
  x += updf<0x111, 0xf, 0xf>(0.0f, x);
  x += updf<0x112, 0xf, 0xf>(0.0f, x);
  x += updf<0x114, 0xf, 0xe>(0.0f, x);
  x += updf<0x118, 0xf, 0xc>(0.0f, x);
  x += updf<0x142, 0xa, 0xf>(0.0f, x);
  x += updf<0x143, 0xc, 0xf>(0.0f, x);
  return x;
}
static __device__ __forceinline__ float readlane63(float x) {
  return __int_as_float(__builtin_amdgcn_readlane(__float_as_int(x), 63));
}

// Kernel A: per-ray scan + scalar outputs + coef handoff. No colors.
__global__ __launch_bounds__(256) void march_lite(
    const float* __restrict__ dens, const float* __restrict__ depths,
    const float* __restrict__ grads, float* __restrict__ out,
    float* __restrict__ coef_ws, const unsigned* __restrict__ mm,
    size_t o_depth, size_t o_w, size_t o_grad)
{
  const int lane = threadIdx.x & 63;
  const size_t ray = (size_t)blockIdx.x * 4 + (threadIdx.x >> 6);

  const float d   = depths[ray * 64 + lane];
  const float den = dens  [ray * 64 + lane];
  const float* gp = grads + ray * 192 + (size_t)lane * 3;
  const float g0 = gp[0], g1 = gp[1], g2 = gp[2];

  const float dn    = __shfl_down(d, 1);
  const float denn  = __shfl_down(den, 1);
  const float delta = dn - d;
  const float dm    = 0.5f * (den + denn) - 1.0f;
  const float sp    = fmaxf(dm, 0.0f) + log1pf(expf(-fabsf(dm)));  // softplus
  const float dd    = sp * delta;
  const float alpha = 1.0f - expf(-dd);
  const float t     = (1.0f - alpha) + 1e-10f;

  const float p = mul_scan64(t);
  float excl = __shfl_up(p, 1);
  if (lane == 0) excl = 1.0f;
  const float w = (lane < 63) ? alpha * excl : 0.0f;

  if (lane < 63) out[o_w + ray * 63 + lane] = w;

  float wprev = __shfl_up(w, 1);
  if (lane == 0) wprev = 0.0f;
  const float coef = 0.5f * (w + wprev);
  coef_ws[ray * 64 + lane] = coef;

  const float wt = readlane63(sum64_lane63(w));
  const float s1 = readlane63(sum64_lane63(coef * d));
  const float s2 = readlane63(sum64_lane63(coef * g0));
  const float s3 = readlane63(sum64_lane63(coef * g1));
  const float s4 = readlane63(sum64_lane63(coef * g2));

  if (lane == 0) {
    float cd = s1 / wt;
    if (cd != cd) cd = INFINITY;
    cd = fminf(fmaxf(cd, funkey(mm[0])), funkey(mm[1]));
    out[o_depth + ray] = cd;
    const float add = 1.0f - wt;
    float* og = out + o_grad + ray * 3;
    og[0] = s2 + add;
    og[1] = s3 + add;
    og[2] = s4 + add;
  }
}

// Kernel B: pure color stream + weighted reduce. One wave per ray.
__global__ __launch_bounds__(256) void rgb_kernel(
    const float* __restrict__ colors, const float* __restrict__ coef_ws,
    float* __restrict__ out)
{
  const int lane = threadIdx.x & 63;
  const size_t ray = (size_t)blockIdx.x * 4 + (threadIdx.x >> 6);

  const float coef = coef_ws[ray * 64 + lane];

  // transposed loads: instr k reads contiguous 1 KB; lane holds
  // sample s = k*8 + (lane>>3), channels (lane&7)*4 .. +3
  const float4* cp = (const float4*)(colors + ray * 2048);
  float4 col[8];
#pragma unroll
  for (int k = 0; k < 8; ++k) col[k] = cp[(size_t)k * 64 + lane];

  float a0 = 0.f, a1 = 0.f, a2 = 0.f, a3 = 0.f;
  const int sbase = lane >> 3;
#pragma unroll
  for (int k = 0; k < 8; ++k) {
    const float cf = __shfl(coef, k * 8 + sbase);
    a0 = fmaf(cf, col[k].x, a0);
    a1 = fmaf(cf, col[k].y, a1);
    a2 = fmaf(cf, col[k].z, a2);
    a3 = fmaf(cf, col[k].w, a3);
  }
  a0 += updf<0x128, 0xf, 0xf>(0.0f, a0);   // + lane^8 (row_ror:8)
  a1 += updf<0x128, 0xf, 0xf>(0.0f, a1);
  a2 += updf<0x128, 0xf, 0xf>(0.0f, a2);
  a3 += updf<0x128, 0xf, 0xf>(0.0f, a3);
#pragma unroll
  for (int off = 16; off <= 32; off <<= 1) {
    a0 += __shfl_xor(a0, off);
    a1 += __shfl_xor(a1, off);
    a2 += __shfl_xor(a2, off);
    a3 += __shfl_xor(a3, off);
  }
  if (lane < 8) {
    float4 o;
    o.x = fmaf(a0, 2.0f, -1.0f);
    o.y = fmaf(a1, 2.0f, -1.0f);
    o.z = fmaf(a2, 2.0f, -1.0f);
    o.w = fmaf(a3, 2.0f, -1.0f);
    ((float4*)(out + ray * 32))[lane] = o;
  }
}

extern "C" void kernel_launch(void* const* d_in, const int* in_sizes, int n_in,
                              void* d_out, int out_size, void* d_ws, size_t ws_size,
                              hipStream_t stream) {
  const float* colors = (const float*)d_in[0];
  const float* dens   = (const float*)d_in[1];
  const float* depths = (const float*)d_in[2];
  const float* grads  = (const float*)d_in[3];
  float* out = (float*)d_out;
  unsigned* ws = (unsigned*)d_ws;
  float* coef_ws = (float*)d_ws + 16;   // 64B offset keeps alignment

  const int ndep  = in_sizes[2];        // B*R*S = nrays*64
  const int nrays = ndep / 64;          // 65536
  const int C     = in_sizes[0] / ndep; // 32

  const size_t o_depth = (size_t)nrays * C;
  const size_t o_w     = o_depth + (size_t)nrays;
  const size_t o_grad  = o_w + (size_t)nrays * 63;

  hipLaunchKernelGGL(init_minmax, dim3(1), dim3(64), 0, stream, ws);
  hipLaunchKernelGGL(minmax_kernel, dim3(512), dim3(256), 0, stream,
                     (const float4*)depths, ws, ndep / 4);
  hipLaunchKernelGGL(march_lite, dim3(nrays / 4), dim3(256), 0, stream,
                     dens, depths, grads, out, coef_ws, ws, o_depth, o_w, o_grad);
  hipLaunchKernelGGL(rgb_kernel, dim3(nrays / 4), dim3(256), 0, stream,
                     colors, coef_ws, out);
}

// Round 8
// 129.699 us; speedup vs baseline: 3.9499x; 1.1905x over previous
//
#include <hip/hip_runtime.h>
#include <math.h>

typedef float fvec4 __attribute__((ext_vector_type(4)));

// ---- DPP cross-lane helpers (VALU, no DS-unit traffic) ----
template <int CTRL, int RM, int BM>
static __device__ __forceinline__ float updf(float oldv, float src) {
  return __int_as_float(__builtin_amdgcn_update_dpp(
      __float_as_int(oldv), __float_as_int(src), CTRL, RM, BM, false));
}

static __device__ __forceinline__ float mul_scan64(float x) {
  x *= updf<0x111, 0xf, 0xf>(1.0f, x);  // row_shr:1
  x *= updf<0x112, 0xf, 0xf>(1.0f, x);  // row_shr:2
  x *= updf<0x114, 0xf, 0xe>(1.0f, x);  // row_shr:4
  x *= updf<0x118, 0xf, 0xc>(1.0f, x);  // row_shr:8
  x *= updf<0x142, 0xa, 0xf>(1.0f, x);  // row_bcast:15 -> rows 1,3
  x *= updf<0x143, 0xc, 0xf>(1.0f, x);  // row_bcast:31 -> rows 2,3
  return x;
}
static __device__ __forceinline__ float sum64_lane63(float x) {
  x += updf<0x111, 0xf, 0xf>(0.0f, x);
  x += updf<0x112, 0xf, 0xf>(0.0f, x);
  x += updf<0x114, 0xf, 0xe>(0.0f, x);
  x += updf<0x118, 0xf, 0xc>(0.0f, x);
  x += updf<0x142, 0xa, 0xf>(0.0f, x);
  x += updf<0x143, 0xc, 0xf>(0.0f, x);
  return x;
}
static __device__ __forceinline__ float readlane63(float x) {
  return __int_as_float(__builtin_amdgcn_readlane(__float_as_int(x), 63));
}

// Kernel 1: depth min/max, 512 blocks, per-block result slots (NO atomics).
// ws[b] = block min, ws[512+b] = block max.
__global__ __launch_bounds__(256) void minmax_kernel(const float4* __restrict__ d,
                                                     float* __restrict__ ws, int n4) {
  __shared__ float smin[4], smax[4];
  int idx = blockIdx.x * 256 + threadIdx.x;
  int stride = gridDim.x * 256;
  float lmin = INFINITY, lmax = -INFINITY;
  for (int i = idx; i < n4; i += stride) {
    float4 v = d[i];
    lmin = fminf(lmin, fminf(fminf(v.x, v.y), fminf(v.z, v.w)));
    lmax = fmaxf(lmax, fmaxf(fmaxf(v.x, v.y), fmaxf(v.z, v.w)));
  }
#pragma unroll
  for (int off = 32; off; off >>= 1) {
    lmin = fminf(lmin, __shfl_xor(lmin, off));
    lmax = fmaxf(lmax, __shfl_xor(lmax, off));
  }
  const int wid = threadIdx.x >> 6;
  if ((threadIdx.x & 63) == 0) { smin[wid] = lmin; smax[wid] = lmax; }
  __syncthreads();
  if (threadIdx.x == 0) {
    ws[blockIdx.x]       = fminf(fminf(smin[0], smin[1]), fminf(smin[2], smin[3]));
    ws[512 + blockIdx.x] = fmaxf(fmaxf(smax[0], smax[1]), fmaxf(smax[2], smax[3]));
  }
}

// Kernel 2: per-ray scan + scalar outputs + coef handoff; reduces the 1024
// min/max partials per block (L2-hot). No colors, no atomics.
__global__ __launch_bounds__(256) void march_lite(
    const float* __restrict__ dens, const float* __restrict__ depths,
    const float* __restrict__ grads, float* __restrict__ out,
    float* __restrict__ coef_ws, const float* __restrict__ mm_part,
    size_t o_depth, size_t o_w, size_t o_grad)
{
  __shared__ float smin[4], smax[4];
  const int lane = threadIdx.x & 63;
  const int wid  = threadIdx.x >> 6;
  const size_t ray = (size_t)blockIdx.x * 4 + wid;

  const float d   = depths[ray * 64 + lane];
  const float den = __builtin_nontemporal_load(dens + ray * 64 + lane);
  const float* gp = grads + ray * 192 + (size_t)lane * 3;
  const float g0 = __builtin_nontemporal_load(gp + 0);
  const float g1 = __builtin_nontemporal_load(gp + 1);
  const float g2 = __builtin_nontemporal_load(gp + 2);

  const float dn    = __shfl_down(d, 1);
  const float denn  = __shfl_down(den, 1);
  const float delta = dn - d;
  const float dm    = 0.5f * (den + denn) - 1.0f;
  const float sp    = fmaxf(dm, 0.0f) + log1pf(expf(-fabsf(dm)));  // softplus
  const float dd    = sp * delta;
  const float alpha = 1.0f - expf(-dd);
  const float t     = (1.0f - alpha) + 1e-10f;

  const float p = mul_scan64(t);
  float excl = __shfl_up(p, 1);
  if (lane == 0) excl = 1.0f;
  const float w = (lane < 63) ? alpha * excl : 0.0f;

  if (lane < 63)
    __builtin_nontemporal_store(w, out + o_w + ray * 63 + lane);

  float wprev = __shfl_up(w, 1);
  if (lane == 0) wprev = 0.0f;
  const float coef = 0.5f * (w + wprev);
  coef_ws[ray * 64 + lane] = coef;

  const float wt = readlane63(sum64_lane63(w));
  const float s1 = readlane63(sum64_lane63(coef * d));
  const float s2 = readlane63(sum64_lane63(coef * g0));
  const float s3 = readlane63(sum64_lane63(coef * g1));
  const float s4 = readlane63(sum64_lane63(coef * g2));

  // block-level reduce of the 512+512 min/max partials (4 KB, L2-hot)
  {
    float m0 = fminf(mm_part[threadIdx.x], mm_part[threadIdx.x + 256]);
    float m1 = fmaxf(mm_part[512 + threadIdx.x], mm_part[512 + threadIdx.x + 256]);
#pragma unroll
    for (int off = 32; off; off >>= 1) {
      m0 = fminf(m0, __shfl_xor(m0, off));
      m1 = fmaxf(m1, __shfl_xor(m1, off));
    }
    if (lane == 0) { smin[wid] = m0; smax[wid] = m1; }
  }
  __syncthreads();

  if (lane == 0) {
    const float dmin = fminf(fminf(smin[0], smin[1]), fminf(smin[2], smin[3]));
    const float dmax = fmaxf(fmaxf(smax[0], smax[1]), fmaxf(smax[2], smax[3]));
    float cd = s1 / wt;
    if (cd != cd) cd = INFINITY;          // NaN -> inf (clip -> dmax)
    cd = fminf(fmaxf(cd, dmin), dmax);
    out[o_depth + ray] = cd;
    const float add = 1.0f - wt;
    float* og = out + o_grad + ray * 3;
    og[0] = s2 + add;
    og[1] = s3 + add;
    og[2] = s4 + add;
  }
}

// Kernel 3: pure color stream + weighted reduce. One wave per ray.
__global__ __launch_bounds__(256) void rgb_kernel(
    const float* __restrict__ colors, const float* __restrict__ coef_ws,
    float* __restrict__ out)
{
  const int lane = threadIdx.x & 63;
  const size_t ray = (size_t)blockIdx.x * 4 + (threadIdx.x >> 6);

  const float coef = coef_ws[ray * 64 + lane];

  // transposed loads: instr k reads contiguous 1 KB; lane holds
  // sample s = k*8 + (lane>>3), channels (lane&7)*4 .. +3
  const fvec4* cp = (const fvec4*)(colors + ray * 2048);
  fvec4 col[8];
#pragma unroll
  for (int k = 0; k < 8; ++k)
    col[k] = __builtin_nontemporal_load(cp + (size_t)k * 64 + lane);

  float a0 = 0.f, a1 = 0.f, a2 = 0.f, a3 = 0.f;
  const int sbase = lane >> 3;
#pragma unroll
  for (int k = 0; k < 8; ++k) {
    const float cf = __shfl(coef, k * 8 + sbase);
    a0 = fmaf(cf, col[k].x, a0);
    a1 = fmaf(cf, col[k].y, a1);
    a2 = fmaf(cf, col[k].z, a2);
    a3 = fmaf(cf, col[k].w, a3);
  }
  a0 += updf<0x128, 0xf, 0xf>(0.0f, a0);   // + lane^8 (row_ror:8)
  a1 += updf<0x128, 0xf, 0xf>(0.0f, a1);
  a2 += updf<0x128, 0xf, 0xf>(0.0f, a2);
  a3 += updf<0x128, 0xf, 0xf>(0.0f, a3);
#pragma unroll
  for (int off = 16; off <= 32; off <<= 1) {
    a0 += __shfl_xor(a0, off);
    a1 += __shfl_xor(a1, off);
    a2 += __shfl_xor(a2, off);
    a3 += __shfl_xor(a3, off);
  }
  if (lane < 8) {
    float4 o;
    o.x = fmaf(a0, 2.0f, -1.0f);
    o.y = fmaf(a1, 2.0f, -1.0f);
    o.z = fmaf(a2, 2.0f, -1.0f);
    o.w = fmaf(a3, 2.0f, -1.0f);
    ((float4*)(out + ray * 32))[lane] = o;
  }
}

extern "C" void kernel_launch(void* const* d_in, const int* in_sizes, int n_in,
                              void* d_out, int out_size, void* d_ws, size_t ws_size,
                              hipStream_t stream) {
  const float* colors = (const float*)d_in[0];
  const float* dens   = (const float*)d_in[1];
  const float* depths = (const float*)d_in[2];
  const float* grads  = (const float*)d_in[3];
  float* out = (float*)d_out;
  float* ws  = (float*)d_ws;           // [0..1023]: minmax partials
  float* coef_ws = ws + 1024;          // coef handoff

  const int ndep  = in_sizes[2];        // B*R*S = nrays*64
  const int nrays = ndep / 64;          // 65536
  const int C     = in_sizes[0] / ndep; // 32

  const size_t o_depth = (size_t)nrays * C;
  const size_t o_w     = o_depth + (size_t)nrays;
  const size_t o_grad  = o_w + (size_t)nrays * 63;

  hipLaunchKernelGGL(minmax_kernel, dim3(512), dim3(256), 0, stream,
                     (const float4*)depths, ws, ndep / 4);
  hipLaunchKernelGGL(march_lite, dim3(nrays / 4), dim3(256), 0, stream,
                     dens, depths, grads, out, coef_ws, ws, o_depth, o_w, o_grad);
  hipLaunchKernelGGL(rgb_kernel, dim3(nrays / 4), dim3(256), 0, stream,
                     colors, coef_ws, out);
}

// Round 9
// 125.802 us; speedup vs baseline: 4.0722x; 1.0310x over previous
//
#include <hip/hip_runtime.h>
#include <math.h>

typedef float fvec4 __attribute__((ext_vector_type(4)));

// ---- DPP cross-lane helpers (VALU, no DS-unit traffic) ----
template <int CTRL, int RM, int BM>
static __device__ __forceinline__ float updf(float oldv, float src) {
  return __int_as_float(__builtin_amdgcn_update_dpp(
      __float_as_int(oldv), __float_as_int(src), CTRL, RM, BM, false));
}

static __device__ __forceinline__ float mul_scan64(float x) {
  x *= updf<0x111, 0xf, 0xf>(1.0f, x);  // row_shr:1
  x *= updf<0x112, 0xf, 0xf>(1.0f, x);  // row_shr:2
  x *= updf<0x114, 0xf, 0xe>(1.0f, x);  // row_shr:4
  x *= updf<0x118, 0xf, 0xc>(1.0f, x);  // row_shr:8
  x *= updf<0x142, 0xa, 0xf>(1.0f, x);  // row_bcast:15 -> rows 1,3
  x *= updf<0x143, 0xc, 0xf>(1.0f, x);  // row_bcast:31 -> rows 2,3
  return x;
}
static __device__ __forceinline__ float sum64_lane63(float x) {
  x += updf<0x111, 0xf, 0xf>(0.0f, x);
  x += updf<0x112, 0xf, 0xf>(0.0f, x);
  x += updf<0x114, 0xf, 0xe>(0.0f, x);
  x += updf<0x118, 0xf, 0xc>(0.0f, x);
  x += updf<0x142, 0xa, 0xf>(0.0f, x);
  x += updf<0x143, 0xc, 0xf>(0.0f, x);
  return x;
}
static __device__ __forceinline__ float readlane63(float x) {
  return __int_as_float(__builtin_amdgcn_readlane(__float_as_int(x), 63));
}

// ws layout:
//   ws[0        .. nb-1 ]  per-block depth min partials
//   ws[nb       .. 2nb-1]  per-block depth max partials
//   ws[2nb], ws[2nb+1]     final dmin, dmax           (written by reduce_kernel)
//   cd_ws = ws + 2nb + 64  raw composite depth per ray

// Kernel 1: fused march + rgb. 256 thr = 4 waves; each wave owns 4 rays.
// Phase A: scan/weights/grads/coef->regs, raw depth, block minmax partial.
// Phase B: NT color stream + weighted reduce + rgb store.
__global__ __launch_bounds__(256) void fused_kernel(
    const float* __restrict__ colors, const float* __restrict__ dens,
    const float* __restrict__ depths, const float* __restrict__ grads,
    float* __restrict__ out, float* __restrict__ ws, float* __restrict__ cd_ws,
    size_t o_w, size_t o_grad, int nb)
{
  __shared__ float smin[4], smax[4];
  const int lane = threadIdx.x & 63;
  const int wid  = threadIdx.x >> 6;
  const size_t ray0 = (size_t)blockIdx.x * 16 + (size_t)wid * 4;

  float cf[4];
  float dmin_w = INFINITY, dmax_w = -INFINITY;

  // ---- phase A: 4 independent scan chains (ILP across rays) ----
#pragma unroll
  for (int r = 0; r < 4; ++r) {
    const size_t ray = ray0 + r;
    const float d   = depths[ray * 64 + lane];
    const float den = __builtin_nontemporal_load(dens + ray * 64 + lane);
    const float* gp = grads + ray * 192 + (size_t)lane * 3;
    const float g0 = __builtin_nontemporal_load(gp + 0);
    const float g1 = __builtin_nontemporal_load(gp + 1);
    const float g2 = __builtin_nontemporal_load(gp + 2);

    dmin_w = fminf(dmin_w, d);
    dmax_w = fmaxf(dmax_w, d);

    const float dn    = __shfl_down(d, 1);
    const float denn  = __shfl_down(den, 1);
    const float delta = dn - d;
    const float dm    = 0.5f * (den + denn) - 1.0f;
    const float sp    = fmaxf(dm, 0.0f) + log1pf(expf(-fabsf(dm)));  // softplus
    const float dd    = sp * delta;
    const float alpha = 1.0f - expf(-dd);
    const float t     = (1.0f - alpha) + 1e-10f;

    const float p = mul_scan64(t);
    float excl = __shfl_up(p, 1);
    if (lane == 0) excl = 1.0f;
    const float w = (lane < 63) ? alpha * excl : 0.0f;

    if (lane < 63)
      __builtin_nontemporal_store(w, out + o_w + ray * 63 + lane);

    float wprev = __shfl_up(w, 1);
    if (lane == 0) wprev = 0.0f;
    const float coef = 0.5f * (w + wprev);
    cf[r] = coef;

    const float wt = readlane63(sum64_lane63(w));
    const float s1 = readlane63(sum64_lane63(coef * d));
    const float s2 = readlane63(sum64_lane63(coef * g0));
    const float s3 = readlane63(sum64_lane63(coef * g1));
    const float s4 = readlane63(sum64_lane63(coef * g2));

    if (lane == 0) {
      float cd = s1 / wt;
      if (cd != cd) cd = INFINITY;        // NaN -> inf (clip later -> dmax)
      cd_ws[ray] = cd;
      const float add = 1.0f - wt;
      float* og = out + o_grad + ray * 3;
      og[0] = s2 + add;
      og[1] = s3 + add;
      og[2] = s4 + add;
    }
  }

  // block depth-minmax partial (no atomics)
#pragma unroll
  for (int off = 32; off; off >>= 1) {
    dmin_w = fminf(dmin_w, __shfl_xor(dmin_w, off));
    dmax_w = fmaxf(dmax_w, __shfl_xor(dmax_w, off));
  }
  if (lane == 0) { smin[wid] = dmin_w; smax[wid] = dmax_w; }
  __syncthreads();
  if (threadIdx.x == 0) {
    ws[blockIdx.x]      = fminf(fminf(smin[0], smin[1]), fminf(smin[2], smin[3]));
    ws[nb + blockIdx.x] = fmaxf(fmaxf(smax[0], smax[1]), fmaxf(smax[2], smax[3]));
  }

  // ---- phase B: color streaming + weighted reduce ----
  const int sbase = lane >> 3;
#pragma unroll
  for (int r = 0; r < 4; ++r) {
    const size_t ray = ray0 + r;
    // transposed loads: instr k reads contiguous 1 KB; lane holds
    // sample s = k*8 + (lane>>3), channels (lane&7)*4 .. +3
    const fvec4* cp = (const fvec4*)(colors + ray * 2048);
    fvec4 col[8];
#pragma unroll
    for (int k = 0; k < 8; ++k)
      col[k] = __builtin_nontemporal_load(cp + (size_t)k * 64 + lane);

    float a0 = 0.f, a1 = 0.f, a2 = 0.f, a3 = 0.f;
#pragma unroll
    for (int k = 0; k < 8; ++k) {
      const float cfb = __shfl(cf[r], k * 8 + sbase);
      a0 = fmaf(cfb, col[k].x, a0);
      a1 = fmaf(cfb, col[k].y, a1);
      a2 = fmaf(cfb, col[k].z, a2);
      a3 = fmaf(cfb, col[k].w, a3);
    }
    a0 += updf<0x128, 0xf, 0xf>(0.0f, a0);   // + lane^8 (row_ror:8)
    a1 += updf<0x128, 0xf, 0xf>(0.0f, a1);
    a2 += updf<0x128, 0xf, 0xf>(0.0f, a2);
    a3 += updf<0x128, 0xf, 0xf>(0.0f, a3);
#pragma unroll
    for (int off = 16; off <= 32; off <<= 1) {
      a0 += __shfl_xor(a0, off);
      a1 += __shfl_xor(a1, off);
      a2 += __shfl_xor(a2, off);
      a3 += __shfl_xor(a3, off);
    }
    if (lane < 8) {
      float4 o;
      o.x = fmaf(a0, 2.0f, -1.0f);
      o.y = fmaf(a1, 2.0f, -1.0f);
      o.z = fmaf(a2, 2.0f, -1.0f);
      o.w = fmaf(a3, 2.0f, -1.0f);
      ((float4*)(out + ray * 32))[lane] = o;
    }
  }
}

// Kernel 2: one block reduces the 2*nb partials -> ws[2nb], ws[2nb+1]
__global__ __launch_bounds__(256) void reduce_kernel(float* __restrict__ ws, int nb) {
  __shared__ float smin[4], smax[4];
  float m0 = INFINITY, m1 = -INFINITY;
  for (int j = threadIdx.x; j < nb; j += 256) {
    m0 = fminf(m0, ws[j]);
    m1 = fmaxf(m1, ws[nb + j]);
  }
#pragma unroll
  for (int off = 32; off; off >>= 1) {
    m0 = fminf(m0, __shfl_xor(m0, off));
    m1 = fmaxf(m1, __shfl_xor(m1, off));
  }
  const int wid = threadIdx.x >> 6;
  if ((threadIdx.x & 63) == 0) { smin[wid] = m0; smax[wid] = m1; }
  __syncthreads();
  if (threadIdx.x == 0) {
    ws[2 * nb]     = fminf(fminf(smin[0], smin[1]), fminf(smin[2], smin[3]));
    ws[2 * nb + 1] = fmaxf(fmaxf(smax[0], smax[1]), fmaxf(smax[2], smax[3]));
  }
}

// Kernel 3: clip raw depths and store (L2-hot, tiny)
__global__ __launch_bounds__(256) void depth_kernel(
    const float* __restrict__ cd_ws, const float* __restrict__ mm,
    float* __restrict__ out, size_t o_depth)
{
  const int i = blockIdx.x * 256 + threadIdx.x;
  const float dmin = mm[0], dmax = mm[1];
  out[o_depth + i] = fminf(fmaxf(cd_ws[i], dmin), dmax);
}

extern "C" void kernel_launch(void* const* d_in, const int* in_sizes, int n_in,
                              void* d_out, int out_size, void* d_ws, size_t ws_size,
                              hipStream_t stream) {
  const float* colors = (const float*)d_in[0];
  const float* dens   = (const float*)d_in[1];
  const float* depths = (const float*)d_in[2];
  const float* grads  = (const float*)d_in[3];
  float* out = (float*)d_out;
  float* ws  = (float*)d_ws;

  const int ndep  = in_sizes[2];        // B*R*S = nrays*64
  const int nrays = ndep / 64;          // 65536
  const int C     = in_sizes[0] / ndep; // 32

  const size_t o_depth = (size_t)nrays * C;
  const size_t o_w     = o_depth + (size_t)nrays;
  const size_t o_grad  = o_w + (size_t)nrays * 63;

  const int nb = nrays / 16;            // fused blocks (4096)
  float* cd_ws = ws + 2 * (size_t)nb + 64;

  hipLaunchKernelGGL(fused_kernel, dim3(nb), dim3(256), 0, stream,
                     colors, dens, depths, grads, out, ws, cd_ws, o_w, o_grad, nb);
  hipLaunchKernelGGL(reduce_kernel, dim3(1), dim3(256), 0, stream, ws, nb);
  hipLaunchKernelGGL(depth_kernel, dim3(nrays / 256), dim3(256), 0, stream,
                     cd_ws, ws + 2 * (size_t)nb, out, o_depth);
}